// Round 1
// baseline (252.912 us; speedup 1.0000x reference)
//
#include <hip/hip_runtime.h>
#include <stdint.h>

// Keep IoU arithmetic bit-identical to an IEEE no-FMA reference:
#pragma clang fp contract(off)

#define BB   8
#define NN   2048
#define CC   32
#define WORDS 64           // uint32 words per 2048-bit row mask
#define NMS_THR 0.45f
#define PRE_THR 0.005f

// ---------------- Kernel A: per-image adjacency bitmask ----------------
// grid (64, 8): block (w,b) handles rows [w*32, w*32+32) of image b.
// adj[((b*NN + row)*WORDS) + word] : bit j of word w => IoU(row, w*32+j) > thr, diag cleared.
__global__ __launch_bounds__(256) void adj_kernel(const float* __restrict__ bbs,
                                                  uint32_t* __restrict__ adj) {
    __shared__ float sx1[NN], sy1[NN], sx2[NN], sy2[NN];
    const int b = blockIdx.y;
    const int t = threadIdx.x;
    const float4* bp = (const float4*)bbs + (size_t)b * NN;
    for (int i = t; i < NN; i += 256) {
        float4 v = bp[i];
        sx1[i] = v.x; sy1[i] = v.y; sx2[i] = v.z; sy2[i] = v.w;
    }
    __syncthreads();
    const int wave = t >> 6;
    const int lane = t & 63;
    const int row0 = blockIdx.x * 32;
    for (int rr = wave; rr < 32; rr += 4) {
        const int row = row0 + rr;
        const float ax1 = sx1[row], ay1 = sy1[row], ax2 = sx2[row], ay2 = sy2[row];
        const float areaA = (ax2 - ax1) * (ay2 - ay1);
        uint32_t myword = 0;
        for (int s = 0; s < 32; ++s) {
            const int col = s * 64 + lane;
            float bx1 = sx1[col], by1 = sy1[col], bx2 = sx2[col], by2 = sy2[col];
            float ltx = fmaxf(ax1, bx1), lty = fmaxf(ay1, by1);
            float rbx = fminf(ax2, bx2), rby = fminf(ay2, by2);
            float w  = fmaxf(rbx - ltx, 0.0f);
            float h  = fmaxf(rby - lty, 0.0f);
            float inter = w * h;
            float areaB = (bx2 - bx1) * (by2 - by1);
            float uni   = (areaA + areaB) - inter;
            float iou   = inter / fmaxf(uni, 1e-12f);
            bool a = (iou > NMS_THR) && (col != row);
            unsigned long long bal = __ballot(a);
            if ((lane >> 1) == s)
                myword = (lane & 1) ? (uint32_t)(bal >> 32) : (uint32_t)bal;
        }
        adj[((size_t)b * NN + row) * WORDS + lane] = myword;
    }
}

// ---------------- Kernel B: per-(b,c) sort + greedy NMS ----------------
// grid 256 (= B*C), 256 threads.
__global__ __launch_bounds__(256) void nms_kernel(const float* __restrict__ conf,
                                                  const uint32_t* __restrict__ adj,
                                                  float* __restrict__ out) {
    __shared__ unsigned long long keys[NN];  // 16 KB
    __shared__ uint32_t ordv[NN];            // 8 KB: idx | (nonzero<<16)
    __shared__ uint32_t Sarr[WORDS];         // final suppressed mask
    const int bc = blockIdx.x;
    const int b  = bc >> 5;
    const int c  = bc & 31;
    const int t  = threadIdx.x;
    const float* cf = conf + ((size_t)b * CC + c) * NN;

    // Build sort keys: (bits(thresholded conf) << 32) | (2047 - i)
    // Descending sort on key == JAX stable argsort(-conf): ties -> lower index first.
    for (int i = t; i < NN; i += 256) {
        float v  = cf[i];
        float vt = (v > PRE_THR) ? v : 0.0f;
        keys[i] = ((unsigned long long)__float_as_uint(vt) << 32) | (uint32_t)(NN - 1 - i);
    }
    __syncthreads();

    // Bitonic sort, descending (keys are unique => stability irrelevant).
    for (unsigned k = 2; k <= NN; k <<= 1) {
        for (unsigned j = k >> 1; j > 0; j >>= 1) {
            for (unsigned p = t; p < NN / 2; p += 256) {
                unsigned i  = ((p & ~(j - 1)) << 1) | (p & (j - 1));
                unsigned ij = i | j;
                unsigned long long a = keys[i], d = keys[ij];
                bool up = ((i & k) == 0);
                if (up ? (a < d) : (a > d)) { keys[i] = d; keys[ij] = a; }
            }
            __syncthreads();
        }
    }

    for (int r = t; r < NN; r += 256) {
        unsigned long long kk = keys[r];
        uint32_t idx = (uint32_t)(NN - 1) - (uint32_t)(kk & 0xffffffffu);
        uint32_t nz  = ((uint32_t)(kk >> 32) != 0u) ? 0x10000u : 0u;
        ordv[r] = idx | nz;
    }
    __syncthreads();

    // Serial greedy scan by wave 0. Suppressed mask S: lane l holds uint32 word l.
    if (t < 64) {
        const int lane = t;
        const uint32_t* rowbase = adj + (size_t)b * NN * WORDS + lane;
        uint32_t S = 0;
        constexpr int P = 32;
        uint32_t obuf[P], obuf2[P], rbuf[P];
#pragma unroll
        for (int d = 0; d < P; ++d) obuf[d] = ordv[d];
#pragma unroll
        for (int d = 0; d < P; ++d) obuf2[d] = ordv[d + P];
#pragma unroll
        for (int d = 0; d < P; ++d)
            rbuf[d] = rowbase[(size_t)(obuf[d] & 0xffffu) * WORDS];

        for (int r0 = 0; r0 < NN; r0 += P) {
#pragma unroll
            for (int d = 0; d < P; ++d) {
                const int r = r0 + d;
                // ---- main body for rank r ----
                int ovs = __builtin_amdgcn_readfirstlane((int)obuf[d]);
                int idx = ovs & 0xffff;
                int w   = idx >> 5, bpos = idx & 31;
                int sw  = __builtin_amdgcn_readlane((int)S, w);
                bool active = ((ovs >> 16) & 1) && !((sw >> bpos) & 1);
                S |= active ? rbuf[d] : 0u;
                // ---- prefetch row for rank r+P (address from ordv read 1 block ago) ----
                int i2 = (int)(obuf2[d] & 0xffffu);
                rbuf[d] = rowbase[(size_t)i2 * WORDS];
                obuf[d] = obuf2[d];
                // ---- prefetch ordv for rank r+2P ----
                int nr = r + 2 * P; if (nr > NN - 1) nr = NN - 1;
                obuf2[d] = ordv[nr];
            }
        }
        Sarr[lane] = S;
    }
    __syncthreads();

    float* op = out + ((size_t)b * CC + c) * NN;
    for (int i = t; i < NN; i += 256) {
        float v = cf[i];
        bool sup = (Sarr[i >> 5] >> (i & 31)) & 1u;
        op[i] = (v > PRE_THR && !sup) ? v : 0.0f;
    }
}

extern "C" void kernel_launch(void* const* d_in, const int* in_sizes, int n_in,
                              void* d_out, int out_size, void* d_ws, size_t ws_size,
                              hipStream_t stream) {
    const float* bbs  = (const float*)d_in[0];   // [8,2048,4]
    const float* conf = (const float*)d_in[1];   // [8,32,2048]
    float* out = (float*)d_out;                  // [8,32,2048]
    uint32_t* adj = (uint32_t*)d_ws;             // 8*2048*64*4 = 4 MB

    const size_t need = (size_t)BB * NN * WORDS * sizeof(uint32_t);
    if (ws_size < need) return;  // fail loudly via validation rather than corrupt memory

    adj_kernel<<<dim3(64, BB), 256, 0, stream>>>(bbs, adj);
    nms_kernel<<<BB * CC, 256, 0, stream>>>(conf, adj, out);
}